// Round 1
// baseline (37.865 us; speedup 1.0000x reference)
//
#include <hip/hip_runtime.h>

// YOLOv1 loss, MI355X. NB=2 boxes, NC=20 classes, GS=7 grid, BATCH=16384.
// preds/targets: (16384,7,7,30) f32. out: 3 f32 [loss_boxes, loss_object, loss_class].

#define NBX 2
#define NCLS 20
constexpr int   CH      = 5 * NBX + NCLS;      // 30 channels per cell
constexpr int   NCELL   = 16384 * 7 * 7;       // 802816
constexpr float INV_GS  = 1.0f / 7.0f;
constexpr float INV_BS  = 1.0f / 16384.0f;
constexpr float L_COORD = 5.0f;
constexpr float L_NOOBJ = 0.5f;
constexpr int   BLK     = 256;
constexpr int   NBLK    = NCELL / BLK;         // 3136 exactly

__global__ __launch_bounds__(BLK) void yolo_loss_partial(
    const float* __restrict__ preds,
    const float* __restrict__ targets,
    float* __restrict__ part)   // [NBLK][3] raw sums
{
    const int n = blockIdx.x * BLK + threadIdx.x;

    float s_box = 0.f, s_obj = 0.f, s_cls = 0.f;

    {
        float p[CH], t[CH];
        const float2* p2 = reinterpret_cast<const float2*>(preds   + (size_t)n * CH);
        const float2* t2 = reinterpret_cast<const float2*>(targets + (size_t)n * CH);
        #pragma unroll
        for (int i = 0; i < CH / 2; ++i) {
            float2 v = p2[i]; p[2*i] = v.x; p[2*i+1] = v.y;
            float2 w = t2[i]; t[2*i] = w.x; t[2*i+1] = w.y;
        }

        const bool obj = t[4] > 0.f;

        // no-object confidence loss (both boxes)
        float d0 = p[4] - t[4];
        float d1 = p[9] - t[9];
        float noobj = obj ? 0.f : (d0 * d0 + d1 * d1);

        // IoU of each pred box vs target box 0 (xy scaled by 1/GS, wh raw — per reference)
        const float tx = t[0] * INV_GS, ty = t[1] * INV_GS;
        const float tw = t[2], th = t[3];
        const float tax0 = tx - 0.5f * tw, tay0 = ty - 0.5f * th;
        const float tax1 = tx + 0.5f * tw, tay1 = ty + 0.5f * th;
        const float area_t = tw * th;

        float iou0, iou1;
        {
            float px = p[0] * INV_GS, py = p[1] * INV_GS, pw = p[2], ph = p[3];
            float ax0 = px - 0.5f * pw, ay0 = py - 0.5f * ph;
            float ax1 = px + 0.5f * pw, ay1 = py + 0.5f * ph;
            float iw = fmaxf(fminf(ax1, tax1) - fmaxf(ax0, tax0), 0.f);
            float ih = fmaxf(fminf(ay1, tay1) - fmaxf(ay0, tay0), 0.f);
            float inter = iw * ih;
            iou0 = inter / (pw * ph + area_t - inter);
        }
        {
            float px = p[5] * INV_GS, py = p[6] * INV_GS, pw = p[7], ph = p[8];
            float ax0 = px - 0.5f * pw, ay0 = py - 0.5f * ph;
            float ax1 = px + 0.5f * pw, ay1 = py + 0.5f * ph;
            float iw = fmaxf(fminf(ax1, tax1) - fmaxf(ax0, tax0), 0.f);
            float ih = fmaxf(fminf(ay1, tay1) - fmaxf(ay0, tay0), 0.f);
            float inter = iw * ih;
            iou1 = inter / (pw * ph + area_t - inter);
        }

        // responsible box: argmax (first-max tie-break => strict >)
        const bool  sel     = iou1 > iou0;
        const float max_iou = fmaxf(iou0, iou1);
        const float rx = sel ? p[5] : p[0];
        const float ry = sel ? p[6] : p[1];
        const float rw = sel ? p[7] : p[2];
        const float rh = sel ? p[8] : p[3];
        const float rc = sel ? p[9] : p[4];

        if (obj) {
            float dx = rx - t[0], dy = ry - t[1];
            float sw = sqrtf(rw) - sqrtf(t[2]);
            float sh = sqrtf(rh) - sqrtf(t[3]);
            s_box = dx * dx + dy * dy + sw * sw + sh * sh;

            float dc = rc - max_iou;
            s_obj = dc * dc;

            float c = 0.f;
            #pragma unroll
            for (int k = 5 * NBX; k < CH; ++k) {
                float d = p[k] - t[k];
                c += d * d;
            }
            s_cls = c;
        }
        s_obj += L_NOOBJ * noobj;   // fold 0.5*noobj into the object-loss slot
    }

    // wave64 reduce
    #pragma unroll
    for (int off = 32; off > 0; off >>= 1) {
        s_box += __shfl_down(s_box, off);
        s_obj += __shfl_down(s_obj, off);
        s_cls += __shfl_down(s_cls, off);
    }

    __shared__ float red[3][BLK / 64];
    const int wid  = threadIdx.x >> 6;
    const int lane = threadIdx.x & 63;
    if (lane == 0) { red[0][wid] = s_box; red[1][wid] = s_obj; red[2][wid] = s_cls; }
    __syncthreads();
    if (threadIdx.x == 0) {
        float b = red[0][0] + red[0][1] + red[0][2] + red[0][3];
        float o = red[1][0] + red[1][1] + red[1][2] + red[1][3];
        float c = red[2][0] + red[2][1] + red[2][2] + red[2][3];
        float* pp = part + (size_t)blockIdx.x * 3;
        pp[0] = b; pp[1] = o; pp[2] = c;
    }
}

__global__ __launch_bounds__(256) void yolo_loss_reduce(
    const float* __restrict__ part, float* __restrict__ out)
{
    float s0 = 0.f, s1 = 0.f, s2 = 0.f;
    for (int i = threadIdx.x; i < NBLK; i += 256) {
        s0 += part[3 * i + 0];
        s1 += part[3 * i + 1];
        s2 += part[3 * i + 2];
    }
    #pragma unroll
    for (int off = 32; off > 0; off >>= 1) {
        s0 += __shfl_down(s0, off);
        s1 += __shfl_down(s1, off);
        s2 += __shfl_down(s2, off);
    }
    __shared__ float red[3][4];
    const int wid  = threadIdx.x >> 6;
    const int lane = threadIdx.x & 63;
    if (lane == 0) { red[0][wid] = s0; red[1][wid] = s1; red[2][wid] = s2; }
    __syncthreads();
    if (threadIdx.x == 0) {
        float b = red[0][0] + red[0][1] + red[0][2] + red[0][3];
        float o = red[1][0] + red[1][1] + red[1][2] + red[1][3];
        float c = red[2][0] + red[2][1] + red[2][2] + red[2][3];
        out[0] = L_COORD * b * INV_BS;
        out[1] = o * INV_BS;
        out[2] = c * INV_BS;
    }
}

extern "C" void kernel_launch(void* const* d_in, const int* in_sizes, int n_in,
                              void* d_out, int out_size, void* d_ws, size_t ws_size,
                              hipStream_t stream) {
    const float* preds   = (const float*)d_in[0];
    const float* targets = (const float*)d_in[1];
    float* out  = (float*)d_out;
    float* part = (float*)d_ws;   // NBLK*3 floats = 37632 B

    yolo_loss_partial<<<NBLK, BLK, 0, stream>>>(preds, targets, part);
    yolo_loss_reduce<<<1, 256, 0, stream>>>(part, out);
}